// Round 5
// baseline (261.812 us; speedup 1.0000x reference)
//
#include <hip/hip_runtime.h>
#include <hip/hip_bf16.h>

typedef __attribute__((ext_vector_type(8))) short s16x8;
typedef __attribute__((ext_vector_type(4))) float f32x4;

#define D_FEAT 512
#define CHUNKS 8
#define CHUNKN 2500
#define NPW 5

__device__ __forceinline__ unsigned short f2bf(float f) {
  __hip_bfloat16 h = __float2bfloat16(f);
  return *reinterpret_cast<unsigned short*>(&h);
}

__device__ __forceinline__ float bf2f(short u) {
  union { unsigned int i; float f; } c;
  c.i = ((unsigned int)(unsigned short)u) << 16;
  return c.f;
}

__device__ __forceinline__ void async16(void* lds, const void* g) {
  __builtin_amdgcn_global_load_lds(
      (const __attribute__((address_space(1))) void*)g,
      (__attribute__((address_space(3))) void*)lds, 16, 0, 0);
}

// ---------------- fused: histogram (deg) + x->bf16 convert ----------------

__global__ __launch_bounds__(256) void hx_k(const int* __restrict__ dst, int E,
                                            int* __restrict__ deg,
                                            const float* __restrict__ x,
                                            unsigned short* __restrict__ xb, int n8, int hb) {
  int bid = blockIdx.x;
  if (bid < hb) {
    int i = bid * 256 + threadIdx.x;
    if (i < E) atomicAdd(&deg[dst[i]], 1);
  } else {
    int i = (bid - hb) * 256 + threadIdx.x;
    if (i < n8) {
      const float4* p = (const float4*)x + (size_t)i * 2;
      float4 u = p[0], v = p[1];
      s16x8 r;
      r[0] = (short)f2bf(u.x); r[1] = (short)f2bf(u.y);
      r[2] = (short)f2bf(u.z); r[3] = (short)f2bf(u.w);
      r[4] = (short)f2bf(v.x); r[5] = (short)f2bf(v.y);
      r[6] = (short)f2bf(v.z); r[7] = (short)f2bf(v.w);
      ((s16x8*)xb)[i] = r;
    }
  }
}

// ---------------- exclusive scan of deg -> rowstart ----------------

__global__ __launch_bounds__(1024) void scan_k(const int* __restrict__ deg,
                                               int* __restrict__ rowstart, int n) {
  __shared__ int wsum[16];
  __shared__ int carry_s;
  int tid = threadIdx.x;
  int lane = tid & 63, wid = tid >> 6;
  if (tid == 0) carry_s = 0;
  __syncthreads();
  for (int t0 = 0; t0 < n; t0 += 1024) {
    int i = t0 + tid;
    int v = (i < n) ? deg[i] : 0;
    int s = v;
#pragma unroll
    for (int off = 1; off < 64; off <<= 1) {
      int t = __shfl_up(s, off);
      if (lane >= off) s += t;
    }
    if (lane == 63) wsum[wid] = s;
    __syncthreads();
    if (wid == 0) {
      int ws = (lane < 16) ? wsum[lane] : 0;
#pragma unroll
      for (int off = 1; off < 16; off <<= 1) {
        int t = __shfl_up(ws, off);
        if (lane >= off) ws += t;
      }
      if (lane < 16) wsum[lane] = ws;
    }
    __syncthreads();
    int carry = carry_s;
    int wbase = (wid > 0) ? wsum[wid - 1] : 0;
    if (i < n) rowstart[i] = carry + wbase + s - v;
    int total = wsum[15];
    __syncthreads();
    if (tid == 0) carry_s = carry + total;
    __syncthreads();
  }
  if (threadIdx.x == 0) rowstart[n] = carry_s;
}

__global__ void fill_k(const int* __restrict__ src, const int* __restrict__ dst, int E,
                       const int* __restrict__ rowstart, int* __restrict__ cursor,
                       int* __restrict__ eperm) {
  int i = blockIdx.x * 256 + threadIdx.x;
  if (i < E) {
    int d = dst[i];
    int pos = atomicAdd(&cursor[d], 1);
    eperm[rowstart[d] + pos] = src[i];
  }
}

// ---------------- sort neighbor lists + emit chunk segment table ----------------
// One wave/node: 64-wide shfl_xor bitonic sort (deg<=64 covers all nodes at ~6
// sigma), then 7 ballots give per-chunk boundaries of the sorted list.
// seg[node][c] = first index with src >= c*CHUNKN; seg[node][0]=beg, [CHUNKS]=end.
// deg>64 fallback: whole list in chunk 0 (correct, just unsorted/unlocal).

__global__ __launch_bounds__(256) void sort_k(const int* __restrict__ rowstart,
                                              int* __restrict__ eperm,
                                              int* __restrict__ seg, int Nn) {
  int wid = threadIdx.x >> 6, lane = threadIdx.x & 63;
  int node = blockIdx.x * 4 + wid;
  if (node >= Nn) return;
  int beg = rowstart[node], end = rowstart[node + 1];
  int deg = end - beg;
  if (deg > 64) {
    if (lane <= CHUNKS) seg[node * (CHUNKS + 1) + lane] = (lane == 0) ? beg : end;
    return;
  }
  int v = (lane < deg) ? eperm[beg + lane] : 0x7fffffff;
#pragma unroll
  for (int k = 2; k <= 64; k <<= 1) {
#pragma unroll
    for (int j = k >> 1; j > 0; j >>= 1) {
      int other = __shfl_xor(v, j);
      bool iLower = (lane & j) == 0;
      bool asc = (lane & k) == 0;
      int mn = min(v, other), mx = max(v, other);
      v = (iLower == asc) ? mn : mx;
    }
  }
  if (lane < deg) eperm[beg + lane] = v;
  int myseg = beg + deg;  // lane CHUNKS default: end
  if (lane == 0) myseg = beg;
#pragma unroll
  for (int c = 1; c < CHUNKS; ++c) {
    unsigned long long b = __ballot(v < c * CHUNKN);
    if (lane == c) myseg = beg + __popcll(b);
  }
  if (lane <= CHUNKS) seg[node * (CHUNKS + 1) + lane] = myseg;
}

// ---------------- chunk-phased aggregation ----------------
// NPW nodes per wave held in registers; all waves resident (grid = 4 blocks/CU
// exactly); chunk c of xb (~2.4 MB) is read by every wave in the same phase ->
// L2-resident reuse. h = x_own + sum(sorted neighbors), deterministic order.

__global__ __launch_bounds__(256, 4) void agg_k(const unsigned short* __restrict__ xb,
                                                const int* __restrict__ eperm,
                                                const int* __restrict__ seg,
                                                unsigned short* __restrict__ h, int Nn) {
  int wid = threadIdx.x >> 6, lane = threadIdx.x & 63;
  int nbase = (blockIdx.x * 4 + wid) * NPW;
  float acc[NPW][8];
#pragma unroll
  for (int k = 0; k < NPW; ++k) {
    int nk = nbase + k;
    if (nk < Nn) {
      s16x8 own = ((const s16x8*)(xb + (size_t)nk * D_FEAT))[lane];
#pragma unroll
      for (int t = 0; t < 8; ++t) acc[k][t] = bf2f(own[t]);
    } else {
#pragma unroll
      for (int t = 0; t < 8; ++t) acc[k][t] = 0.f;
    }
  }
  for (int c = 0; c < CHUNKS; ++c) {
#pragma unroll
    for (int k = 0; k < NPW; ++k) {
      int nk = nbase + k;
      if (nk >= Nn) continue;
      int j = seg[nk * (CHUNKS + 1) + c];
      int je = seg[nk * (CHUNKS + 1) + c + 1];
      for (; j + 2 <= je; j += 2) {
        int s0 = eperm[j], s1 = eperm[j + 1];
        s16x8 v0 = ((const s16x8*)(xb + (size_t)s0 * D_FEAT))[lane];
        s16x8 v1 = ((const s16x8*)(xb + (size_t)s1 * D_FEAT))[lane];
#pragma unroll
        for (int t = 0; t < 8; ++t) acc[k][t] += bf2f(v0[t]) + bf2f(v1[t]);
      }
      if (j < je) {
        int s0 = eperm[j];
        s16x8 v0 = ((const s16x8*)(xb + (size_t)s0 * D_FEAT))[lane];
#pragma unroll
        for (int t = 0; t < 8; ++t) acc[k][t] += bf2f(v0[t]);
      }
    }
  }
#pragma unroll
  for (int k = 0; k < NPW; ++k) {
    int nk = nbase + k;
    if (nk < Nn) {
      s16x8 r;
#pragma unroll
      for (int t = 0; t < 8; ++t) r[t] = (short)f2bf(acc[k][t]);
      ((s16x8*)(h + (size_t)nk * D_FEAT))[lane] = r;
    }
  }
}

// ---------------- both weights: Wt[n][k] = bf16(W[k][n]) ----------------

__global__ __launch_bounds__(256) void wconv_k(const float* __restrict__ W1,
                                               const float* __restrict__ W2,
                                               unsigned short* __restrict__ W1t,
                                               unsigned short* __restrict__ W2t) {
  int idx = blockIdx.x * 256 + threadIdx.x;  // over 2 * 512*512
  const float* W = W1;
  unsigned short* Wt = W1t;
  if (idx >= 512 * 512) { idx -= 512 * 512; W = W2; Wt = W2t; }
  int n = idx >> 9, k = idx & 511;
  Wt[idx] = f2bf(W[((size_t)k << 9) + n]);
}

// ---------------- GEMM: C = act(A @ B + bias) ----------------
// A[M,512] bf16 row-major, Bt[512,512] bf16 (B^T). 128x128 tile, BK=64,
// depth-1 prefetch w/ raw barrier + vmcnt(0), XOR-swizzled LDS chunks,
// XCD-chunked block mapping (4 N-tiles of an M-panel share an XCD).

template <int RELU, int OUTBF16>
__global__ __launch_bounds__(256) void gemm_k(const unsigned short* __restrict__ A,
                                              const unsigned short* __restrict__ Bt,
                                              const float* __restrict__ bias,
                                              void* __restrict__ Cout, int M) {
  const int K = 512;
  __shared__ unsigned short As[2][128 * 64];
  __shared__ unsigned short Bs[2][128 * 64];
  int mt = (M + 127) >> 7;
  int qx = (mt + 7) >> 3;  // M-panels per XCD
  int b = blockIdx.x;
  int x = b & 7, i = b >> 3;
  int tm = x * qx + (i >> 2);
  int tn = i & 3;
  if (tm >= mt) return;
  int tid = threadIdx.x;
  int wave = tid >> 6, lane = tid & 63;
  int lr = lane & 15, lh = lane >> 4;
  int p7 = lr & 7;  // row&7 for all fragment rows this lane reads
  int wm = (wave >> 1) * 64, wn = (wave & 1) * 64;

  auto stage = [&](int pb, int k0) {
#pragma unroll
    for (int ii = 0; ii < 4; ++ii) {
      int cb = ii * 256 + wave * 64 + lane;  // chunk id: row = cb>>3, slot c = cb&7
      int row = cb >> 3;
      int cg = (cb & 7) ^ (row & 7);  // inverse-swizzled global chunk
      int ga = tm * 128 + row;
      if (ga > M - 1) ga = M - 1;
      async16(&As[pb][(size_t)(ii * 256 + wave * 64) * 8], A + (size_t)ga * K + k0 + cg * 8);
      int gb = tn * 128 + row;
      async16(&Bs[pb][(size_t)(ii * 256 + wave * 64) * 8], Bt + (size_t)gb * K + k0 + cg * 8);
    }
  };

  f32x4 zero = {0.f, 0.f, 0.f, 0.f};
  f32x4 acc[4][4];
#pragma unroll
  for (int m = 0; m < 4; ++m)
#pragma unroll
    for (int n = 0; n < 4; ++n) acc[m][n] = zero;

  stage(0, 0);
  asm volatile("s_waitcnt vmcnt(0)" ::: "memory");
  __builtin_amdgcn_s_barrier();

  for (int t = 0; t < 8; ++t) {
    int pb = t & 1;
    if (t < 7) stage(pb ^ 1, (t + 1) * 64);
#pragma unroll
    for (int kk = 0; kk < 64; kk += 32) {
      s16x8 av[4], bv[4];
#pragma unroll
      for (int m = 0; m < 4; ++m) {
        int c = ((kk >> 3) + lh) ^ p7;
        av[m] = *(const s16x8*)&As[pb][(wm + m * 16 + lr) * 64 + c * 8];
      }
#pragma unroll
      for (int n = 0; n < 4; ++n) {
        int c = ((kk >> 3) + lh) ^ p7;
        bv[n] = *(const s16x8*)&Bs[pb][(wn + n * 16 + lr) * 64 + c * 8];
      }
#pragma unroll
      for (int m = 0; m < 4; ++m)
#pragma unroll
        for (int n = 0; n < 4; ++n)
          acc[m][n] = __builtin_amdgcn_mfma_f32_16x16x32_bf16(av[m], bv[n], acc[m][n], 0, 0, 0);
    }
    asm volatile("s_waitcnt vmcnt(0)" ::: "memory");
    __builtin_amdgcn_s_barrier();
  }

  // epilogue: C/D layout col=lane&15, row=(lane>>4)*4+j  [measured m89]
#pragma unroll
  for (int n = 0; n < 4; ++n) {
    int col = tn * 128 + wn + n * 16 + lr;
    float bval = bias[col];
#pragma unroll
    for (int m = 0; m < 4; ++m) {
#pragma unroll
      for (int j = 0; j < 4; ++j) {
        int row = tm * 128 + wm + m * 16 + lh * 4 + j;
        if (row < M) {
          float v = acc[m][n][j] + bval;
          if (RELU) v = fmaxf(v, 0.f);
          if (OUTBF16)
            ((unsigned short*)Cout)[(size_t)row * 512 + col] = f2bf(v);
          else
            ((float*)Cout)[(size_t)row * 512 + col] = v;
        }
      }
    }
  }
}

// ---------------- launch ----------------

extern "C" void kernel_launch(void* const* d_in, const int* in_sizes, int n_in,
                              void* d_out, int out_size, void* d_ws, size_t ws_size,
                              hipStream_t stream) {
  const float* x = (const float*)d_in[0];
  const int* ei = (const int*)d_in[1];
  const float* W1 = (const float*)d_in[2];
  const float* b1 = (const float*)d_in[3];
  const float* W2 = (const float*)d_in[4];
  const float* b2 = (const float*)d_in[5];
  const int N = in_sizes[0] / D_FEAT;  // 20000
  const int E = in_sizes[1] / 2;       // 640000
  const int* src = ei;
  const int* dst = ei + E;

  char* w = (char*)d_ws;
  auto alloc = [&](size_t bytes) {
    void* p = (void*)w;
    w += (bytes + 255) & ~(size_t)255;
    return p;
  };
  int* eperm = (int*)alloc((size_t)E * 4);
  int* deg = (int*)alloc((size_t)N * 4);
  int* cursor = (int*)alloc((size_t)N * 4);  // adjacent to deg: one memset
  int* rowstart = (int*)alloc((size_t)(N + 1) * 4);
  int* seg = (int*)alloc((size_t)N * (CHUNKS + 1) * 4);
  unsigned short* W1t = (unsigned short*)alloc((size_t)512 * 512 * 2);
  unsigned short* W2t = (unsigned short*)alloc((size_t)512 * 512 * 2);
  unsigned short* c1 = (unsigned short*)alloc((size_t)N * 512 * 2);
  // h (bf16) = lower half of d_out; xb (bf16 copy of x) = upper half.
  // Both dead before gemm2 overwrites d_out with the fp32 result.
  unsigned short* h = (unsigned short*)d_out;
  unsigned short* xb = (unsigned short*)d_out + (size_t)N * D_FEAT;

  size_t zbytes = (size_t)((char*)cursor - (char*)deg) + (size_t)N * 4;
  hipMemsetAsync(deg, 0, zbytes, stream);
  int hb = (E + 255) / 256;                  // 2500
  int n8 = N * D_FEAT / 8;                   // 1.28M
  int xbk = (n8 + 255) / 256;                // 5000
  hx_k<<<hb + xbk, 256, 0, stream>>>(dst, E, deg, x, xb, n8, hb);
  scan_k<<<1, 1024, 0, stream>>>(deg, rowstart, N);
  fill_k<<<hb, 256, 0, stream>>>(src, dst, E, rowstart, cursor, eperm);
  sort_k<<<(N + 3) / 4, 256, 0, stream>>>(rowstart, eperm, seg, N);
  wconv_k<<<2048, 256, 0, stream>>>(W1, W2, W1t, W2t);
  int aggwaves = (N + NPW - 1) / NPW;        // 4000
  agg_k<<<(aggwaves + 3) / 4, 256, 0, stream>>>(xb, eperm, seg, h, N);
  int mt = (N + 127) / 128, qx = (mt + 7) / 8;
  int grid = 8 * qx * 4;
  gemm_k<1, 1><<<grid, 256, 0, stream>>>(h, W1t, b1, c1, N);
  gemm_k<0, 0><<<grid, 256, 0, stream>>>(c1, W2t, b2, d_out, N);
}

// Round 6
// 248.142 us; speedup vs baseline: 1.0551x; 1.0551x over previous
//
#include <hip/hip_runtime.h>
#include <hip/hip_bf16.h>

typedef __attribute__((ext_vector_type(8))) short s16x8;
typedef __attribute__((ext_vector_type(4))) float f32x4;

#define D_FEAT 512
#define CHUNKS 8
#define CHUNKN 2500
#define NPW 4

__device__ __forceinline__ unsigned short f2bf(float f) {
  __hip_bfloat16 h = __float2bfloat16(f);
  return *reinterpret_cast<unsigned short*>(&h);
}

__device__ __forceinline__ float bf2f(short u) {
  union { unsigned int i; float f; } c;
  c.i = ((unsigned int)(unsigned short)u) << 16;
  return c.f;
}

__device__ __forceinline__ void async16(void* lds, const void* g) {
  __builtin_amdgcn_global_load_lds(
      (const __attribute__((address_space(1))) void*)g,
      (__attribute__((address_space(3))) void*)lds, 16, 0, 0);
}

// ---------------- fused: histogram (deg) + x->bf16 convert ----------------

__global__ __launch_bounds__(256) void hx_k(const int* __restrict__ dst, int E,
                                            int* __restrict__ deg,
                                            const float* __restrict__ x,
                                            unsigned short* __restrict__ xb, int n8, int hb) {
  int bid = blockIdx.x;
  if (bid < hb) {
    int i = bid * 256 + threadIdx.x;
    if (i < E) atomicAdd(&deg[dst[i]], 1);
  } else {
    int i = (bid - hb) * 256 + threadIdx.x;
    if (i < n8) {
      const float4* p = (const float4*)x + (size_t)i * 2;
      float4 u = p[0], v = p[1];
      s16x8 r;
      r[0] = (short)f2bf(u.x); r[1] = (short)f2bf(u.y);
      r[2] = (short)f2bf(u.z); r[3] = (short)f2bf(u.w);
      r[4] = (short)f2bf(v.x); r[5] = (short)f2bf(v.y);
      r[6] = (short)f2bf(v.z); r[7] = (short)f2bf(v.w);
      ((s16x8*)xb)[i] = r;
    }
  }
}

// ---------------- exclusive scan of deg -> rowstart ----------------

__global__ __launch_bounds__(1024) void scan_k(const int* __restrict__ deg,
                                               int* __restrict__ rowstart, int n) {
  __shared__ int wsum[16];
  __shared__ int carry_s;
  int tid = threadIdx.x;
  int lane = tid & 63, wid = tid >> 6;
  if (tid == 0) carry_s = 0;
  __syncthreads();
  for (int t0 = 0; t0 < n; t0 += 1024) {
    int i = t0 + tid;
    int v = (i < n) ? deg[i] : 0;
    int s = v;
#pragma unroll
    for (int off = 1; off < 64; off <<= 1) {
      int t = __shfl_up(s, off);
      if (lane >= off) s += t;
    }
    if (lane == 63) wsum[wid] = s;
    __syncthreads();
    if (wid == 0) {
      int ws = (lane < 16) ? wsum[lane] : 0;
#pragma unroll
      for (int off = 1; off < 16; off <<= 1) {
        int t = __shfl_up(ws, off);
        if (lane >= off) ws += t;
      }
      if (lane < 16) wsum[lane] = ws;
    }
    __syncthreads();
    int carry = carry_s;
    int wbase = (wid > 0) ? wsum[wid - 1] : 0;
    if (i < n) rowstart[i] = carry + wbase + s - v;
    int total = wsum[15];
    __syncthreads();
    if (tid == 0) carry_s = carry + total;
    __syncthreads();
  }
  if (threadIdx.x == 0) rowstart[n] = carry_s;
}

__global__ void fill_k(const int* __restrict__ src, const int* __restrict__ dst, int E,
                       const int* __restrict__ rowstart, int* __restrict__ cursor,
                       int* __restrict__ eperm) {
  int i = blockIdx.x * 256 + threadIdx.x;
  if (i < E) {
    int d = dst[i];
    int pos = atomicAdd(&cursor[d], 1);
    eperm[rowstart[d] + pos] = src[i];
  }
}

// ---------------- sort neighbor lists + emit chunk segment table ----------------

__global__ __launch_bounds__(256) void sort_k(const int* __restrict__ rowstart,
                                              int* __restrict__ eperm,
                                              int* __restrict__ seg, int Nn) {
  int wid = threadIdx.x >> 6, lane = threadIdx.x & 63;
  int node = blockIdx.x * 4 + wid;
  if (node >= Nn) return;
  int beg = rowstart[node], end = rowstart[node + 1];
  int deg = end - beg;
  if (deg > 64) {
    if (lane <= CHUNKS) seg[node * (CHUNKS + 1) + lane] = (lane == 0) ? beg : end;
    return;
  }
  int v = (lane < deg) ? eperm[beg + lane] : 0x7fffffff;
#pragma unroll
  for (int k = 2; k <= 64; k <<= 1) {
#pragma unroll
    for (int j = k >> 1; j > 0; j >>= 1) {
      int other = __shfl_xor(v, j);
      bool iLower = (lane & j) == 0;
      bool asc = (lane & k) == 0;
      int mn = min(v, other), mx = max(v, other);
      v = (iLower == asc) ? mn : mx;
    }
  }
  if (lane < deg) eperm[beg + lane] = v;
  int myseg = beg + deg;  // lane CHUNKS default: end
  if (lane == 0) myseg = beg;
#pragma unroll
  for (int c = 1; c < CHUNKS; ++c) {
    unsigned long long b = __ballot(v < c * CHUNKN);
    if (lane == c) myseg = beg + __popcll(b);
  }
  if (lane <= CHUNKS) seg[node * (CHUNKS + 1) + lane] = myseg;
}

// ---------------- chunk-phased aggregation, batched-ILP ----------------
// NPW=4 nodes/wave in registers; grid exactly 1250 blocks, all co-resident
// (launch_bounds 256,5 -> capacity 1280) so every wave processes chunk c in
// the same phase -> chunk (2.44 MB) L2-resident. Inner: branchless batches of
// 4 gathers in flight; masked slots gather row 0 (L1-hot) with fmaf mask 0.

__global__ __launch_bounds__(256, 5) void agg_k(const unsigned short* __restrict__ xb,
                                                const int* __restrict__ eperm,
                                                const int* __restrict__ seg,
                                                unsigned short* __restrict__ h, int Nn) {
  int wid = threadIdx.x >> 6, lane = threadIdx.x & 63;
  int nbase = (blockIdx.x * 4 + wid) * NPW;
  float acc[NPW][8];
#pragma unroll
  for (int k = 0; k < NPW; ++k) {
    int nk = nbase + k;
    s16x8 own = ((const s16x8*)(xb + (size_t)min(nk, Nn - 1) * D_FEAT))[lane];
#pragma unroll
    for (int t = 0; t < 8; ++t) acc[k][t] = bf2f(own[t]);
  }
  for (int c = 0; c < CHUNKS; ++c) {
    int jb[NPW], jeb[NPW];
#pragma unroll
    for (int k = 0; k < NPW; ++k) {
      int nk = min(nbase + k, Nn - 1);
      jb[k] = seg[nk * (CHUNKS + 1) + c];
      jeb[k] = seg[nk * (CHUNKS + 1) + c + 1];
    }
#pragma unroll
    for (int k = 0; k < NPW; ++k) {
      for (int j = jb[k]; j < jeb[k]; j += 4) {
        int je = jeb[k];
        bool a1 = j + 1 < je, a2 = j + 2 < je, a3 = j + 3 < je;
        int s0 = eperm[j];
        int s1 = a1 ? eperm[j + 1] : 0;
        int s2 = a2 ? eperm[j + 2] : 0;
        int s3 = a3 ? eperm[j + 3] : 0;
        s16x8 v0 = ((const s16x8*)(xb + (size_t)s0 * D_FEAT))[lane];
        s16x8 v1 = ((const s16x8*)(xb + (size_t)s1 * D_FEAT))[lane];
        s16x8 v2 = ((const s16x8*)(xb + (size_t)s2 * D_FEAT))[lane];
        s16x8 v3 = ((const s16x8*)(xb + (size_t)s3 * D_FEAT))[lane];
        float m1 = a1 ? 1.f : 0.f, m2 = a2 ? 1.f : 0.f, m3 = a3 ? 1.f : 0.f;
#pragma unroll
        for (int t = 0; t < 8; ++t) {
          acc[k][t] += bf2f(v0[t]);
          acc[k][t] = fmaf(m1, bf2f(v1[t]), acc[k][t]);
          acc[k][t] = fmaf(m2, bf2f(v2[t]), acc[k][t]);
          acc[k][t] = fmaf(m3, bf2f(v3[t]), acc[k][t]);
        }
      }
    }
  }
#pragma unroll
  for (int k = 0; k < NPW; ++k) {
    int nk = nbase + k;
    if (nk < Nn) {
      s16x8 r;
#pragma unroll
      for (int t = 0; t < 8; ++t) r[t] = (short)f2bf(acc[k][t]);
      ((s16x8*)(h + (size_t)nk * D_FEAT))[lane] = r;
    }
  }
}

// ---------------- both weights: Wt[n][k] = bf16(W[k][n]) ----------------

__global__ __launch_bounds__(256) void wconv_k(const float* __restrict__ W1,
                                               const float* __restrict__ W2,
                                               unsigned short* __restrict__ W1t,
                                               unsigned short* __restrict__ W2t) {
  int idx = blockIdx.x * 256 + threadIdx.x;  // over 2 * 512*512
  const float* W = W1;
  unsigned short* Wt = W1t;
  if (idx >= 512 * 512) { idx -= 512 * 512; W = W2; Wt = W2t; }
  int n = idx >> 9, k = idx & 511;
  Wt[idx] = f2bf(W[((size_t)k << 9) + n]);
}

// ---------------- GEMM: C = act(A @ B + bias) ----------------
// A[M,512] bf16 row-major, Bt[512,512] bf16 (B^T). 128x128 tile, BK=64,
// depth-1 prefetch w/ raw barrier + vmcnt(0), XOR-swizzled LDS chunks,
// XCD-chunked block mapping (4 N-tiles of an M-panel share an XCD).

template <int RELU, int OUTBF16>
__global__ __launch_bounds__(256) void gemm_k(const unsigned short* __restrict__ A,
                                              const unsigned short* __restrict__ Bt,
                                              const float* __restrict__ bias,
                                              void* __restrict__ Cout, int M) {
  const int K = 512;
  __shared__ unsigned short As[2][128 * 64];
  __shared__ unsigned short Bs[2][128 * 64];
  int mt = (M + 127) >> 7;
  int qx = (mt + 7) >> 3;  // M-panels per XCD
  int b = blockIdx.x;
  int x = b & 7, i = b >> 3;
  int tm = x * qx + (i >> 2);
  int tn = i & 3;
  if (tm >= mt) return;
  int tid = threadIdx.x;
  int wave = tid >> 6, lane = tid & 63;
  int lr = lane & 15, lh = lane >> 4;
  int p7 = lr & 7;  // row&7 for all fragment rows this lane reads
  int wm = (wave >> 1) * 64, wn = (wave & 1) * 64;

  auto stage = [&](int pb, int k0) {
#pragma unroll
    for (int ii = 0; ii < 4; ++ii) {
      int cb = ii * 256 + wave * 64 + lane;  // chunk id: row = cb>>3, slot c = cb&7
      int row = cb >> 3;
      int cg = (cb & 7) ^ (row & 7);  // inverse-swizzled global chunk
      int ga = tm * 128 + row;
      if (ga > M - 1) ga = M - 1;
      async16(&As[pb][(size_t)(ii * 256 + wave * 64) * 8], A + (size_t)ga * K + k0 + cg * 8);
      int gb = tn * 128 + row;
      async16(&Bs[pb][(size_t)(ii * 256 + wave * 64) * 8], Bt + (size_t)gb * K + k0 + cg * 8);
    }
  };

  f32x4 zero = {0.f, 0.f, 0.f, 0.f};
  f32x4 acc[4][4];
#pragma unroll
  for (int m = 0; m < 4; ++m)
#pragma unroll
    for (int n = 0; n < 4; ++n) acc[m][n] = zero;

  stage(0, 0);
  asm volatile("s_waitcnt vmcnt(0)" ::: "memory");
  __builtin_amdgcn_s_barrier();

  for (int t = 0; t < 8; ++t) {
    int pb = t & 1;
    if (t < 7) stage(pb ^ 1, (t + 1) * 64);
#pragma unroll
    for (int kk = 0; kk < 64; kk += 32) {
      s16x8 av[4], bv[4];
#pragma unroll
      for (int m = 0; m < 4; ++m) {
        int c = ((kk >> 3) + lh) ^ p7;
        av[m] = *(const s16x8*)&As[pb][(wm + m * 16 + lr) * 64 + c * 8];
      }
#pragma unroll
      for (int n = 0; n < 4; ++n) {
        int c = ((kk >> 3) + lh) ^ p7;
        bv[n] = *(const s16x8*)&Bs[pb][(wn + n * 16 + lr) * 64 + c * 8];
      }
#pragma unroll
      for (int m = 0; m < 4; ++m)
#pragma unroll
        for (int n = 0; n < 4; ++n)
          acc[m][n] = __builtin_amdgcn_mfma_f32_16x16x32_bf16(av[m], bv[n], acc[m][n], 0, 0, 0);
    }
    asm volatile("s_waitcnt vmcnt(0)" ::: "memory");
    __builtin_amdgcn_s_barrier();
  }

  // epilogue: C/D layout col=lane&15, row=(lane>>4)*4+j  [measured m89]
#pragma unroll
  for (int n = 0; n < 4; ++n) {
    int col = tn * 128 + wn + n * 16 + lr;
    float bval = bias[col];
#pragma unroll
    for (int m = 0; m < 4; ++m) {
#pragma unroll
      for (int j = 0; j < 4; ++j) {
        int row = tm * 128 + wm + m * 16 + lh * 4 + j;
        if (row < M) {
          float v = acc[m][n][j] + bval;
          if (RELU) v = fmaxf(v, 0.f);
          if (OUTBF16)
            ((unsigned short*)Cout)[(size_t)row * 512 + col] = f2bf(v);
          else
            ((float*)Cout)[(size_t)row * 512 + col] = v;
        }
      }
    }
  }
}

// ---------------- launch ----------------

extern "C" void kernel_launch(void* const* d_in, const int* in_sizes, int n_in,
                              void* d_out, int out_size, void* d_ws, size_t ws_size,
                              hipStream_t stream) {
  const float* x = (const float*)d_in[0];
  const int* ei = (const int*)d_in[1];
  const float* W1 = (const float*)d_in[2];
  const float* b1 = (const float*)d_in[3];
  const float* W2 = (const float*)d_in[4];
  const float* b2 = (const float*)d_in[5];
  const int N = in_sizes[0] / D_FEAT;  // 20000
  const int E = in_sizes[1] / 2;       // 640000
  const int* src = ei;
  const int* dst = ei + E;

  char* w = (char*)d_ws;
  auto alloc = [&](size_t bytes) {
    void* p = (void*)w;
    w += (bytes + 255) & ~(size_t)255;
    return p;
  };
  int* eperm = (int*)alloc((size_t)E * 4);
  int* deg = (int*)alloc((size_t)N * 4);
  int* cursor = (int*)alloc((size_t)N * 4);  // adjacent to deg: one memset
  int* rowstart = (int*)alloc((size_t)(N + 1) * 4);
  int* seg = (int*)alloc((size_t)N * (CHUNKS + 1) * 4);
  unsigned short* W1t = (unsigned short*)alloc((size_t)512 * 512 * 2);
  unsigned short* W2t = (unsigned short*)alloc((size_t)512 * 512 * 2);
  unsigned short* c1 = (unsigned short*)alloc((size_t)N * 512 * 2);
  // h (bf16) = lower half of d_out; xb (bf16 copy of x) = upper half.
  // Both dead before gemm2 overwrites d_out with the fp32 result.
  unsigned short* h = (unsigned short*)d_out;
  unsigned short* xb = (unsigned short*)d_out + (size_t)N * D_FEAT;

  size_t zbytes = (size_t)((char*)cursor - (char*)deg) + (size_t)N * 4;
  hipMemsetAsync(deg, 0, zbytes, stream);
  int hb = (E + 255) / 256;                  // 2500
  int n8 = N * D_FEAT / 8;                   // 1.28M
  int xbk = (n8 + 255) / 256;                // 5000
  hx_k<<<hb + xbk, 256, 0, stream>>>(dst, E, deg, x, xb, n8, hb);
  scan_k<<<1, 1024, 0, stream>>>(deg, rowstart, N);
  fill_k<<<hb, 256, 0, stream>>>(src, dst, E, rowstart, cursor, eperm);
  sort_k<<<(N + 3) / 4, 256, 0, stream>>>(rowstart, eperm, seg, N);
  wconv_k<<<2048, 256, 0, stream>>>(W1, W2, W1t, W2t);
  int aggblocks = (N + 4 * NPW - 1) / (4 * NPW);  // 1250, all co-resident
  agg_k<<<aggblocks, 256, 0, stream>>>(xb, eperm, seg, h, N);
  int mt = (N + 127) / 128, qx = (mt + 7) / 8;
  int grid = 8 * qx * 4;
  gemm_k<1, 1><<<grid, 256, 0, stream>>>(h, W1t, b1, c1, N);
  gemm_k<0, 0><<<grid, 256, 0, stream>>>(c1, W2t, b2, d_out, N);
}

// Round 7
// 246.196 us; speedup vs baseline: 1.0634x; 1.0079x over previous
//
#include <hip/hip_runtime.h>
#include <hip/hip_bf16.h>

typedef __attribute__((ext_vector_type(8))) short s16x8;
typedef __attribute__((ext_vector_type(4))) float f32x4;

#define D_FEAT 512

__device__ __forceinline__ unsigned short f2bf(float f) {
  __hip_bfloat16 h = __float2bfloat16(f);
  return *reinterpret_cast<unsigned short*>(&h);
}

__device__ __forceinline__ float bitsf(unsigned int u) {
  union { unsigned int i; float f; } c;
  c.i = u;
  return c.f;
}

__device__ __forceinline__ void async16(void* lds, const void* g) {
  __builtin_amdgcn_global_load_lds(
      (const __attribute__((address_space(1))) void*)g,
      (__attribute__((address_space(3))) void*)lds, 16, 0, 0);
}

// ---------------- fused: histogram (deg) + x->bf16 convert ----------------

__global__ __launch_bounds__(256) void hx_k(const int* __restrict__ dst, int E,
                                            int* __restrict__ deg,
                                            const float* __restrict__ x,
                                            unsigned short* __restrict__ xb, int n8, int hb) {
  int bid = blockIdx.x;
  if (bid < hb) {
    int i = bid * 256 + threadIdx.x;
    if (i < E) atomicAdd(&deg[dst[i]], 1);
  } else {
    int i = (bid - hb) * 256 + threadIdx.x;
    if (i < n8) {
      const float4* p = (const float4*)x + (size_t)i * 2;
      float4 u = p[0], v = p[1];
      s16x8 r;
      r[0] = (short)f2bf(u.x); r[1] = (short)f2bf(u.y);
      r[2] = (short)f2bf(u.z); r[3] = (short)f2bf(u.w);
      r[4] = (short)f2bf(v.x); r[5] = (short)f2bf(v.y);
      r[6] = (short)f2bf(v.z); r[7] = (short)f2bf(v.w);
      ((s16x8*)xb)[i] = r;
    }
  }
}

// ---------------- exclusive scan of deg -> rowstart ----------------

__global__ __launch_bounds__(1024) void scan_k(const int* __restrict__ deg,
                                               int* __restrict__ rowstart, int n) {
  __shared__ int wsum[16];
  __shared__ int carry_s;
  int tid = threadIdx.x;
  int lane = tid & 63, wid = tid >> 6;
  if (tid == 0) carry_s = 0;
  __syncthreads();
  for (int t0 = 0; t0 < n; t0 += 1024) {
    int i = t0 + tid;
    int v = (i < n) ? deg[i] : 0;
    int s = v;
#pragma unroll
    for (int off = 1; off < 64; off <<= 1) {
      int t = __shfl_up(s, off);
      if (lane >= off) s += t;
    }
    if (lane == 63) wsum[wid] = s;
    __syncthreads();
    if (wid == 0) {
      int ws = (lane < 16) ? wsum[lane] : 0;
#pragma unroll
      for (int off = 1; off < 16; off <<= 1) {
        int t = __shfl_up(ws, off);
        if (lane >= off) ws += t;
      }
      if (lane < 16) wsum[lane] = ws;
    }
    __syncthreads();
    int carry = carry_s;
    int wbase = (wid > 0) ? wsum[wid - 1] : 0;
    if (i < n) rowstart[i] = carry + wbase + s - v;
    int total = wsum[15];
    __syncthreads();
    if (tid == 0) carry_s = carry + total;
    __syncthreads();
  }
  if (threadIdx.x == 0) rowstart[n] = carry_s;
}

__global__ void fill_k(const int* __restrict__ src, const int* __restrict__ dst, int E,
                       const int* __restrict__ rowstart, int* __restrict__ cursor,
                       int* __restrict__ eperm) {
  int i = blockIdx.x * 256 + threadIdx.x;
  if (i < E) {
    int d = dst[i];
    int pos = atomicAdd(&cursor[d], 1);
    eperm[rowstart[d] + pos] = src[i];
  }
}

// ---------------- aggregation: h = x + sum_{j in N(i)} x_j (bf16 gather) ----------------
// 1 node/wave, scalar (readfirstlane) bounds -> index loads on the SALU/s_load
// pipe, 8 gathers in flight per batch, float2 packed accumulate, masked tail
// batch (no serial tail). Grid = N/4 blocks of 4 waves, 6 blocks/CU.

__global__ __launch_bounds__(256, 6) void agg_k(const unsigned short* __restrict__ xb,
                                                const int* __restrict__ rowstart,
                                                const int* __restrict__ eperm,
                                                unsigned short* __restrict__ h) {
  int wid = threadIdx.x >> 6, lane = threadIdx.x & 63;
  int node = blockIdx.x * 4 + wid;
  const s16x8* base = (const s16x8*)xb;
  s16x8 own = base[(size_t)node * 64 + lane];
  float2 acc[4];
#pragma unroll
  for (int q = 0; q < 4; ++q) {
    unsigned int d = (unsigned int)((const int*)&own)[q];
    acc[q].x = bitsf(d << 16);
    acc[q].y = bitsf(d & 0xffff0000u);
  }
  int beg = __builtin_amdgcn_readfirstlane(rowstart[node]);
  int end = __builtin_amdgcn_readfirstlane(rowstart[node + 1]);
  int j = beg;
  for (; j + 8 <= end; j += 8) {
    s16x8 v[8];
#pragma unroll
    for (int b = 0; b < 8; ++b) {
      int idx = eperm[j + b];
      v[b] = base[(size_t)idx * 64 + lane];
    }
#pragma unroll
    for (int b = 0; b < 8; ++b) {
#pragma unroll
      for (int q = 0; q < 4; ++q) {
        unsigned int d = (unsigned int)((const int*)&v[b])[q];
        acc[q].x += bitsf(d << 16);
        acc[q].y += bitsf(d & 0xffff0000u);
      }
    }
  }
  if (j < end) {
    int last = end - 1;
    s16x8 v[8];
    float m[8];
#pragma unroll
    for (int b = 0; b < 8; ++b) {
      int jj = j + b;
      int idx = eperm[min(jj, last)];
      m[b] = (jj < end) ? 1.f : 0.f;
      v[b] = base[(size_t)idx * 64 + lane];
    }
#pragma unroll
    for (int b = 0; b < 8; ++b) {
#pragma unroll
      for (int q = 0; q < 4; ++q) {
        unsigned int d = (unsigned int)((const int*)&v[b])[q];
        acc[q].x = fmaf(m[b], bitsf(d << 16), acc[q].x);
        acc[q].y = fmaf(m[b], bitsf(d & 0xffff0000u), acc[q].y);
      }
    }
  }
  s16x8 r;
#pragma unroll
  for (int q = 0; q < 4; ++q) {
    r[q * 2 + 0] = (short)f2bf(acc[q].x);
    r[q * 2 + 1] = (short)f2bf(acc[q].y);
  }
  ((s16x8*)(h + (size_t)node * D_FEAT))[lane] = r;
}

// ---------------- weights: Wt[n][k] = bf16(W[k][n]), LDS-tiled transpose ----------------

__global__ __launch_bounds__(256) void wconv_k(const float* __restrict__ W1,
                                               const float* __restrict__ W2,
                                               unsigned short* __restrict__ W1t,
                                               unsigned short* __restrict__ W2t) {
  __shared__ float tile[64][65];
  int t = blockIdx.x;  // 0..127: 64 tiles (8x8 of 64x64) per matrix
  const float* W = W1;
  unsigned short* Wt = W1t;
  if (t >= 64) { t -= 64; W = W2; Wt = W2t; }
  int tr = (t >> 3) * 64;  // k base
  int tc = (t & 7) * 64;   // n base
  int tid = threadIdx.x;
  int c4 = (tid & 15) * 4, rg = tid >> 4;
#pragma unroll
  for (int rr = 0; rr < 64; rr += 16) {
    int r = rr + rg;
    float4 vv = *(const float4*)&W[(size_t)(tr + r) * 512 + tc + c4];
    tile[r][c4] = vv.x; tile[r][c4 + 1] = vv.y; tile[r][c4 + 2] = vv.z; tile[r][c4 + 3] = vv.w;
  }
  __syncthreads();
  int ch = tid & 15;  // k-chunk within out row
#pragma unroll
  for (int rr = 0; rr < 64; rr += 16) {
    int n = rr + rg;
    int k0 = ch * 4;
    ushort4 o;
    o.x = f2bf(tile[k0 + 0][n]);
    o.y = f2bf(tile[k0 + 1][n]);
    o.z = f2bf(tile[k0 + 2][n]);
    o.w = f2bf(tile[k0 + 3][n]);
    *(ushort4*)&Wt[(size_t)(tc + n) * 512 + tr + k0] = o;
  }
}

// ---------------- GEMM: C = act(A @ B + bias) ----------------
// A[M,512] bf16 row-major, Bt[512,512] bf16 (B^T). 128x128 tile, BK=64,
// depth-1 prefetch w/ raw barrier + vmcnt(0), XOR-swizzled LDS chunks,
// XCD-chunked block mapping (4 N-tiles of an M-panel share an XCD).

template <int RELU, int OUTBF16>
__global__ __launch_bounds__(256) void gemm_k(const unsigned short* __restrict__ A,
                                              const unsigned short* __restrict__ Bt,
                                              const float* __restrict__ bias,
                                              void* __restrict__ Cout, int M) {
  const int K = 512;
  __shared__ unsigned short As[2][128 * 64];
  __shared__ unsigned short Bs[2][128 * 64];
  int mt = (M + 127) >> 7;
  int qx = (mt + 7) >> 3;  // M-panels per XCD
  int b = blockIdx.x;
  int x = b & 7, i = b >> 3;
  int tm = x * qx + (i >> 2);
  int tn = i & 3;
  if (tm >= mt) return;
  int tid = threadIdx.x;
  int wave = tid >> 6, lane = tid & 63;
  int lr = lane & 15, lh = lane >> 4;
  int p7 = lr & 7;  // row&7 for all fragment rows this lane reads
  int wm = (wave >> 1) * 64, wn = (wave & 1) * 64;

  auto stage = [&](int pb, int k0) {
#pragma unroll
    for (int ii = 0; ii < 4; ++ii) {
      int cb = ii * 256 + wave * 64 + lane;  // chunk id: row = cb>>3, slot c = cb&7
      int row = cb >> 3;
      int cg = (cb & 7) ^ (row & 7);  // inverse-swizzled global chunk
      int ga = tm * 128 + row;
      if (ga > M - 1) ga = M - 1;
      async16(&As[pb][(size_t)(ii * 256 + wave * 64) * 8], A + (size_t)ga * K + k0 + cg * 8);
      int gb = tn * 128 + row;
      async16(&Bs[pb][(size_t)(ii * 256 + wave * 64) * 8], Bt + (size_t)gb * K + k0 + cg * 8);
    }
  };

  f32x4 zero = {0.f, 0.f, 0.f, 0.f};
  f32x4 acc[4][4];
#pragma unroll
  for (int m = 0; m < 4; ++m)
#pragma unroll
    for (int n = 0; n < 4; ++n) acc[m][n] = zero;

  stage(0, 0);
  asm volatile("s_waitcnt vmcnt(0)" ::: "memory");
  __builtin_amdgcn_s_barrier();

  for (int t = 0; t < 8; ++t) {
    int pb = t & 1;
    if (t < 7) stage(pb ^ 1, (t + 1) * 64);
#pragma unroll
    for (int kk = 0; kk < 64; kk += 32) {
      s16x8 av[4], bv[4];
#pragma unroll
      for (int m = 0; m < 4; ++m) {
        int c = ((kk >> 3) + lh) ^ p7;
        av[m] = *(const s16x8*)&As[pb][(wm + m * 16 + lr) * 64 + c * 8];
      }
#pragma unroll
      for (int n = 0; n < 4; ++n) {
        int c = ((kk >> 3) + lh) ^ p7;
        bv[n] = *(const s16x8*)&Bs[pb][(wn + n * 16 + lr) * 64 + c * 8];
      }
#pragma unroll
      for (int m = 0; m < 4; ++m)
#pragma unroll
        for (int n = 0; n < 4; ++n)
          acc[m][n] = __builtin_amdgcn_mfma_f32_16x16x32_bf16(av[m], bv[n], acc[m][n], 0, 0, 0);
    }
    asm volatile("s_waitcnt vmcnt(0)" ::: "memory");
    __builtin_amdgcn_s_barrier();
  }

  // epilogue: C/D layout col=lane&15, row=(lane>>4)*4+j  [measured m89]
#pragma unroll
  for (int n = 0; n < 4; ++n) {
    int col = tn * 128 + wn + n * 16 + lr;
    float bval = bias[col];
#pragma unroll
    for (int m = 0; m < 4; ++m) {
#pragma unroll
      for (int j = 0; j < 4; ++j) {
        int row = tm * 128 + wm + m * 16 + lh * 4 + j;
        if (row < M) {
          float v = acc[m][n][j] + bval;
          if (RELU) v = fmaxf(v, 0.f);
          if (OUTBF16)
            ((unsigned short*)Cout)[(size_t)row * 512 + col] = f2bf(v);
          else
            ((float*)Cout)[(size_t)row * 512 + col] = v;
        }
      }
    }
  }
}

// ---------------- launch ----------------

extern "C" void kernel_launch(void* const* d_in, const int* in_sizes, int n_in,
                              void* d_out, int out_size, void* d_ws, size_t ws_size,
                              hipStream_t stream) {
  const float* x = (const float*)d_in[0];
  const int* ei = (const int*)d_in[1];
  const float* W1 = (const float*)d_in[2];
  const float* b1 = (const float*)d_in[3];
  const float* W2 = (const float*)d_in[4];
  const float* b2 = (const float*)d_in[5];
  const int N = in_sizes[0] / D_FEAT;  // 20000
  const int E = in_sizes[1] / 2;       // 640000
  const int* src = ei;
  const int* dst = ei + E;

  char* w = (char*)d_ws;
  auto alloc = [&](size_t bytes) {
    void* p = (void*)w;
    w += (bytes + 255) & ~(size_t)255;
    return p;
  };
  int* eperm = (int*)alloc((size_t)E * 4);
  int* deg = (int*)alloc((size_t)N * 4);
  int* cursor = (int*)alloc((size_t)N * 4);  // adjacent to deg: one memset
  int* rowstart = (int*)alloc((size_t)(N + 1) * 4);
  unsigned short* W1t = (unsigned short*)alloc((size_t)512 * 512 * 2);
  unsigned short* W2t = (unsigned short*)alloc((size_t)512 * 512 * 2);
  unsigned short* c1 = (unsigned short*)alloc((size_t)N * 512 * 2);
  // h (bf16) = lower half of d_out; xb (bf16 copy of x) = upper half.
  // Both dead before gemm2 overwrites d_out with the fp32 result.
  unsigned short* h = (unsigned short*)d_out;
  unsigned short* xb = (unsigned short*)d_out + (size_t)N * D_FEAT;

  size_t zbytes = (size_t)((char*)cursor - (char*)deg) + (size_t)N * 4;
  hipMemsetAsync(deg, 0, zbytes, stream);
  int hb = (E + 255) / 256;                  // 2500
  int n8 = N * D_FEAT / 8;                   // 1.28M
  int xbk = (n8 + 255) / 256;                // 5000
  hx_k<<<hb + xbk, 256, 0, stream>>>(dst, E, deg, x, xb, n8, hb);
  scan_k<<<1, 1024, 0, stream>>>(deg, rowstart, N);
  fill_k<<<hb, 256, 0, stream>>>(src, dst, E, rowstart, cursor, eperm);
  wconv_k<<<128, 256, 0, stream>>>(W1, W2, W1t, W2t);
  agg_k<<<N / 4, 256, 0, stream>>>(xb, rowstart, eperm, h);
  int mt = (N + 127) / 128, qx = (mt + 7) / 8;
  int grid = 8 * qx * 4;
  gemm_k<1, 1><<<grid, 256, 0, stream>>>(h, W1t, b1, c1, N);
  gemm_k<0, 0><<<grid, 256, 0, stream>>>(c1, W2t, b2, d_out, N);
}

// Round 8
// 218.616 us; speedup vs baseline: 1.1976x; 1.1262x over previous
//
#include <hip/hip_runtime.h>
#include <hip/hip_bf16.h>

typedef __attribute__((ext_vector_type(8))) short s16x8;
typedef __attribute__((ext_vector_type(4))) float f32x4;

#define D_FEAT 512
#define SLICES 8
#define SLICE_D 64

__device__ __forceinline__ unsigned short f2bf(float f) {
  __hip_bfloat16 h = __float2bfloat16(f);
  return *reinterpret_cast<unsigned short*>(&h);
}

__device__ __forceinline__ float bitsf(unsigned int u) {
  union { unsigned int i; float f; } c;
  c.i = u;
  return c.f;
}

__device__ __forceinline__ void async16(void* lds, const void* g) {
  __builtin_amdgcn_global_load_lds(
      (const __attribute__((address_space(1))) void*)g,
      (__attribute__((address_space(3))) void*)lds, 16, 0, 0);
}

// ---------------- fused: histogram (deg) + x -> bf16 slice-major convert ----------------
// xs layout: xs[s][n][64] bf16 (slice-major), slice s = dims [64s, 64s+64).

__global__ __launch_bounds__(256) void hx_k(const int* __restrict__ dst, int E,
                                            int* __restrict__ deg,
                                            const float* __restrict__ x,
                                            unsigned short* __restrict__ xs, int n8, int hb,
                                            int Nn) {
  int bid = blockIdx.x;
  if (bid < hb) {
    int i = bid * 256 + threadIdx.x;
    if (i < E) atomicAdd(&deg[dst[i]], 1);
  } else {
    int i = (bid - hb) * 256 + threadIdx.x;
    if (i < n8) {
      int n = i >> 6;        // node
      int c = i & 63;        // 8-dim chunk within node
      int s = c >> 3;        // slice
      int off = (c & 7);     // 16B chunk within slice row
      const float4* p = (const float4*)x + (size_t)i * 2;
      float4 u = p[0], v = p[1];
      s16x8 r;
      r[0] = (short)f2bf(u.x); r[1] = (short)f2bf(u.y);
      r[2] = (short)f2bf(u.z); r[3] = (short)f2bf(u.w);
      r[4] = (short)f2bf(v.x); r[5] = (short)f2bf(v.y);
      r[6] = (short)f2bf(v.z); r[7] = (short)f2bf(v.w);
      ((s16x8*)xs)[((size_t)s * Nn + n) * 8 + off] = r;
    }
  }
}

// ---------------- scan (rowstart) + degree-bucketed node order ----------------

__global__ __launch_bounds__(1024) void scan_k(const int* __restrict__ deg,
                                               int* __restrict__ rowstart,
                                               unsigned short* __restrict__ nodeord, int n) {
  __shared__ int wsum[16];
  __shared__ int carry_s;
  __shared__ int hist[65];
  int tid = threadIdx.x;
  int lane = tid & 63, wid = tid >> 6;
  if (tid == 0) carry_s = 0;
  __syncthreads();
  for (int t0 = 0; t0 < n; t0 += 1024) {
    int i = t0 + tid;
    int v = (i < n) ? deg[i] : 0;
    int s = v;
#pragma unroll
    for (int off = 1; off < 64; off <<= 1) {
      int t = __shfl_up(s, off);
      if (lane >= off) s += t;
    }
    if (lane == 63) wsum[wid] = s;
    __syncthreads();
    if (wid == 0) {
      int ws = (lane < 16) ? wsum[lane] : 0;
#pragma unroll
      for (int off = 1; off < 16; off <<= 1) {
        int t = __shfl_up(ws, off);
        if (lane >= off) ws += t;
      }
      if (lane < 16) wsum[lane] = ws;
    }
    __syncthreads();
    int carry = carry_s;
    int wbase = (wid > 0) ? wsum[wid - 1] : 0;
    if (i < n) rowstart[i] = carry + wbase + s - v;
    int total = wsum[15];
    __syncthreads();
    if (tid == 0) carry_s = carry + total;
    __syncthreads();
  }
  if (tid == 0) rowstart[n] = carry_s;
  // ---- degree bucketing: nodeord = node ids sorted by min(deg,64) ----
  if (tid < 65) hist[tid] = 0;
  __syncthreads();
  for (int i = tid; i < n; i += 1024) atomicAdd(&hist[min(deg[i], 64)], 1);
  __syncthreads();
  if (tid == 0) {
    int run = 0;
    for (int b = 0; b < 65; ++b) { int c = hist[b]; hist[b] = run; run += c; }
  }
  __syncthreads();
  for (int i = tid; i < n; i += 1024) {
    int b = min(deg[i], 64);
    int pos = atomicAdd(&hist[b], 1);
    nodeord[pos] = (unsigned short)i;
  }
}

__global__ void fill_k(const int* __restrict__ src, const int* __restrict__ dst, int E,
                       const int* __restrict__ rowstart, int* __restrict__ cursor,
                       unsigned short* __restrict__ ep16) {
  int i = blockIdx.x * 256 + threadIdx.x;
  if (i < E) {
    int d = dst[i];
    int pos = atomicAdd(&cursor[d], 1);
    ep16[rowstart[d] + pos] = (unsigned short)src[i];
  }
}

// ---------------- slice-per-XCD aggregation ----------------
// blockIdx&7 = slice = XCD (round-robin dispatch). Slice table (2.56MB) +
// ep16 (1.28MB) stay L2-resident on that XCD for the whole kernel. Wave = 8
// groups x 8 lanes; group processes one node's full edge list, 16B/lane of
// the 128B row-slice. Degree-bucketed node order keeps group degs equal.

__global__ __launch_bounds__(256, 6) void agg_k(const unsigned short* __restrict__ xs,
                                                const int* __restrict__ rowstart,
                                                const unsigned short* __restrict__ ep16,
                                                const unsigned short* __restrict__ nodeord,
                                                unsigned short* __restrict__ h, int Nn) {
  int slice = blockIdx.x & 7;
  int nb = blockIdx.x >> 3;  // 0..624
  int wid = threadIdx.x >> 6, lane = threadIdx.x & 63;
  int g = lane >> 3, sub = lane & 7;
  int slot = (nb * 4 + wid) * 8 + g;  // 0..19999 exactly
  int node = nodeord[slot];
  int beg = rowstart[node];
  int deg = rowstart[node + 1] - beg;
  int degm1 = max(deg - 1, 0);
  int dm = deg;
  dm = max(dm, __shfl_xor(dm, 8));
  dm = max(dm, __shfl_xor(dm, 16));
  dm = max(dm, __shfl_xor(dm, 32));
  const s16x8* sb = (const s16x8*)xs + (size_t)slice * Nn * 8;
  s16x8 own = sb[node * 8 + sub];
  float2 acc[4];
#pragma unroll
  for (int q = 0; q < 4; ++q) {
    unsigned int d = (unsigned int)((const int*)&own)[q];
    acc[q].x = bitsf(d << 16);
    acc[q].y = bitsf(d & 0xffff0000u);
  }
  for (int t = 0; t < dm; t += 4) {
    s16x8 v[4];
    float m[4];
#pragma unroll
    for (int b = 0; b < 4; ++b) {
      int tt = t + b;
      int e = ep16[beg + min(tt, degm1)];
      m[b] = (tt < deg) ? 1.f : 0.f;
      v[b] = sb[e * 8 + sub];
    }
#pragma unroll
    for (int b = 0; b < 4; ++b) {
#pragma unroll
      for (int q = 0; q < 4; ++q) {
        unsigned int d = (unsigned int)((const int*)&v[b])[q];
        acc[q].x = fmaf(m[b], bitsf(d << 16), acc[q].x);
        acc[q].y = fmaf(m[b], bitsf(d & 0xffff0000u), acc[q].y);
      }
    }
  }
  s16x8 r;
#pragma unroll
  for (int q = 0; q < 4; ++q) {
    r[q * 2 + 0] = (short)f2bf(acc[q].x);
    r[q * 2 + 1] = (short)f2bf(acc[q].y);
  }
  // nontemporal: don't evict the hot slice with streaming h writes
  __builtin_nontemporal_store(r, (s16x8*)(h + (size_t)node * D_FEAT + slice * SLICE_D + sub * 8));
}

// ---------------- weights: Wt[n][k] = bf16(W[k][n]), LDS-tiled transpose ----------------

__global__ __launch_bounds__(256) void wconv_k(const float* __restrict__ W1,
                                               const float* __restrict__ W2,
                                               unsigned short* __restrict__ W1t,
                                               unsigned short* __restrict__ W2t) {
  __shared__ float tile[64][65];
  int t = blockIdx.x;  // 0..127
  const float* W = W1;
  unsigned short* Wt = W1t;
  if (t >= 64) { t -= 64; W = W2; Wt = W2t; }
  int tr = (t >> 3) * 64;
  int tc = (t & 7) * 64;
  int tid = threadIdx.x;
  int c4 = (tid & 15) * 4, rg = tid >> 4;
#pragma unroll
  for (int rr = 0; rr < 64; rr += 16) {
    int r = rr + rg;
    float4 vv = *(const float4*)&W[(size_t)(tr + r) * 512 + tc + c4];
    tile[r][c4] = vv.x; tile[r][c4 + 1] = vv.y; tile[r][c4 + 2] = vv.z; tile[r][c4 + 3] = vv.w;
  }
  __syncthreads();
  int ch = tid & 15;
#pragma unroll
  for (int rr = 0; rr < 64; rr += 16) {
    int n = rr + rg;
    int k0 = ch * 4;
    ushort4 o;
    o.x = f2bf(tile[k0 + 0][n]);
    o.y = f2bf(tile[k0 + 1][n]);
    o.z = f2bf(tile[k0 + 2][n]);
    o.w = f2bf(tile[k0 + 3][n]);
    *(ushort4*)&Wt[(size_t)(tc + n) * 512 + tr + k0] = o;
  }
}

// ---------------- GEMM: C = act(A @ B + bias) ----------------

template <int RELU, int OUTBF16>
__global__ __launch_bounds__(256) void gemm_k(const unsigned short* __restrict__ A,
                                              const unsigned short* __restrict__ Bt,
                                              const float* __restrict__ bias,
                                              void* __restrict__ Cout, int M) {
  const int K = 512;
  __shared__ unsigned short As[2][128 * 64];
  __shared__ unsigned short Bs[2][128 * 64];
  int mt = (M + 127) >> 7;
  int qx = (mt + 7) >> 3;
  int b = blockIdx.x;
  int x = b & 7, i = b >> 3;
  int tm = x * qx + (i >> 2);
  int tn = i & 3;
  if (tm >= mt) return;
  int tid = threadIdx.x;
  int wave = tid >> 6, lane = tid & 63;
  int lr = lane & 15, lh = lane >> 4;
  int p7 = lr & 7;
  int wm = (wave >> 1) * 64, wn = (wave & 1) * 64;

  auto stage = [&](int pb, int k0) {
#pragma unroll
    for (int ii = 0; ii < 4; ++ii) {
      int cb = ii * 256 + wave * 64 + lane;
      int row = cb >> 3;
      int cg = (cb & 7) ^ (row & 7);
      int ga = tm * 128 + row;
      if (ga > M - 1) ga = M - 1;
      async16(&As[pb][(size_t)(ii * 256 + wave * 64) * 8], A + (size_t)ga * K + k0 + cg * 8);
      int gb = tn * 128 + row;
      async16(&Bs[pb][(size_t)(ii * 256 + wave * 64) * 8], Bt + (size_t)gb * K + k0 + cg * 8);
    }
  };

  f32x4 zero = {0.f, 0.f, 0.f, 0.f};
  f32x4 acc[4][4];
#pragma unroll
  for (int m = 0; m < 4; ++m)
#pragma unroll
    for (int n = 0; n < 4; ++n) acc[m][n] = zero;

  stage(0, 0);
  asm volatile("s_waitcnt vmcnt(0)" ::: "memory");
  __builtin_amdgcn_s_barrier();

  for (int t = 0; t < 8; ++t) {
    int pb = t & 1;
    if (t < 7) stage(pb ^ 1, (t + 1) * 64);
#pragma unroll
    for (int kk = 0; kk < 64; kk += 32) {
      s16x8 av[4], bv[4];
#pragma unroll
      for (int m = 0; m < 4; ++m) {
        int c = ((kk >> 3) + lh) ^ p7;
        av[m] = *(const s16x8*)&As[pb][(wm + m * 16 + lr) * 64 + c * 8];
      }
#pragma unroll
      for (int n = 0; n < 4; ++n) {
        int c = ((kk >> 3) + lh) ^ p7;
        bv[n] = *(const s16x8*)&Bs[pb][(wn + n * 16 + lr) * 64 + c * 8];
      }
#pragma unroll
      for (int m = 0; m < 4; ++m)
#pragma unroll
        for (int n = 0; n < 4; ++n)
          acc[m][n] = __builtin_amdgcn_mfma_f32_16x16x32_bf16(av[m], bv[n], acc[m][n], 0, 0, 0);
    }
    asm volatile("s_waitcnt vmcnt(0)" ::: "memory");
    __builtin_amdgcn_s_barrier();
  }

#pragma unroll
  for (int n = 0; n < 4; ++n) {
    int col = tn * 128 + wn + n * 16 + lr;
    float bval = bias[col];
#pragma unroll
    for (int m = 0; m < 4; ++m) {
#pragma unroll
      for (int j = 0; j < 4; ++j) {
        int row = tm * 128 + wm + m * 16 + lh * 4 + j;
        if (row < M) {
          float v = acc[m][n][j] + bval;
          if (RELU) v = fmaxf(v, 0.f);
          if (OUTBF16)
            ((unsigned short*)Cout)[(size_t)row * 512 + col] = f2bf(v);
          else
            ((float*)Cout)[(size_t)row * 512 + col] = v;
        }
      }
    }
  }
}

// ---------------- launch ----------------

extern "C" void kernel_launch(void* const* d_in, const int* in_sizes, int n_in,
                              void* d_out, int out_size, void* d_ws, size_t ws_size,
                              hipStream_t stream) {
  const float* x = (const float*)d_in[0];
  const int* ei = (const int*)d_in[1];
  const float* W1 = (const float*)d_in[2];
  const float* b1 = (const float*)d_in[3];
  const float* W2 = (const float*)d_in[4];
  const float* b2 = (const float*)d_in[5];
  const int N = in_sizes[0] / D_FEAT;  // 20000
  const int E = in_sizes[1] / 2;       // 640000
  const int* src = ei;
  const int* dst = ei + E;

  char* w = (char*)d_ws;
  auto alloc = [&](size_t bytes) {
    void* p = (void*)w;
    w += (bytes + 255) & ~(size_t)255;
    return p;
  };
  unsigned short* ep16 = (unsigned short*)alloc((size_t)E * 2 + 256);  // +pad for clamped reads
  int* deg = (int*)alloc((size_t)N * 4);
  int* cursor = (int*)alloc((size_t)N * 4);  // adjacent to deg: one memset
  int* rowstart = (int*)alloc((size_t)(N + 1) * 4);
  unsigned short* nodeord = (unsigned short*)alloc((size_t)N * 2);
  unsigned short* W1t = (unsigned short*)alloc((size_t)512 * 512 * 2);
  unsigned short* W2t = (unsigned short*)alloc((size_t)512 * 512 * 2);
  unsigned short* c1 = (unsigned short*)alloc((size_t)N * 512 * 2);
  // h (bf16) = lower half of d_out; xs (slice-major bf16 x) = upper half.
  // Both dead before gemm2 overwrites d_out with the fp32 result.
  unsigned short* h = (unsigned short*)d_out;
  unsigned short* xs = (unsigned short*)d_out + (size_t)N * D_FEAT;

  size_t zbytes = (size_t)((char*)cursor - (char*)deg) + (size_t)N * 4;
  hipMemsetAsync(deg, 0, zbytes, stream);
  int hb = (E + 255) / 256;                  // 2500
  int n8 = N * D_FEAT / 8;                   // 1.28M
  int xbk = (n8 + 255) / 256;                // 5000
  hx_k<<<hb + xbk, 256, 0, stream>>>(dst, E, deg, x, xs, n8, hb, N);
  scan_k<<<1, 1024, 0, stream>>>(deg, rowstart, nodeord, N);
  fill_k<<<hb, 256, 0, stream>>>(src, dst, E, rowstart, cursor, ep16);
  wconv_k<<<128, 256, 0, stream>>>(W1, W2, W1t, W2t);
  agg_k<<<8 * (N / 32), 256, 0, stream>>>(xs, rowstart, ep16, nodeord, h, N);
  int mt = (N + 127) / 128, qx = (mt + 7) / 8;
  int grid = 8 * qx * 4;
  gemm_k<1, 1><<<grid, 256, 0, stream>>>(h, W1t, b1, c1, N);
  gemm_k<0, 0><<<grid, 256, 0, stream>>>(c1, W2t, b2, d_out, N);
}

// Round 9
// 203.030 us; speedup vs baseline: 1.2895x; 1.0768x over previous
//
#include <hip/hip_runtime.h>
#include <hip/hip_bf16.h>

typedef __attribute__((ext_vector_type(8))) short s16x8;
typedef __attribute__((ext_vector_type(4))) float f32x4;

#define D_FEAT 512
#define SLICES 8
#define SLICE_D 64

__device__ __forceinline__ unsigned short f2bf(float f) {
  __hip_bfloat16 h = __float2bfloat16(f);
  return *reinterpret_cast<unsigned short*>(&h);
}

__device__ __forceinline__ float bitsf(unsigned int u) {
  union { unsigned int i; float f; } c;
  c.i = u;
  return c.f;
}

__device__ __forceinline__ void async16(void* lds, const void* g) {
  __builtin_amdgcn_global_load_lds(
      (const __attribute__((address_space(1))) void*)g,
      (__attribute__((address_space(3))) void*)lds, 16, 0, 0);
}

// ---------------- zero scratch (replaces pathological rocclr fillBuffer) ----------------

__global__ __launch_bounds__(256) void zero_k(int4* __restrict__ p, int n16) {
  int i = blockIdx.x * 256 + threadIdx.x;
  if (i < n16) p[i] = make_int4(0, 0, 0, 0);
}

// ---------------- fused: histogram (deg) + x -> bf16 slice-major convert ----------------
// xs layout: xs[s][n][64] bf16 (slice-major), slice s = dims [64s, 64s+64).

__global__ __launch_bounds__(256) void hx_k(const int* __restrict__ dst, int E,
                                            int* __restrict__ deg,
                                            const float* __restrict__ x,
                                            unsigned short* __restrict__ xs, int n8, int hb,
                                            int Nn) {
  int bid = blockIdx.x;
  if (bid < hb) {
    int i = bid * 256 + threadIdx.x;
    if (i < E) atomicAdd(&deg[dst[i]], 1);
  } else {
    int i = (bid - hb) * 256 + threadIdx.x;
    if (i < n8) {
      int n = i >> 6;        // node
      int c = i & 63;        // 8-dim chunk within node
      int s = c >> 3;        // slice
      int off = (c & 7);     // 16B chunk within slice row
      const float4* p = (const float4*)x + (size_t)i * 2;
      float4 u = p[0], v = p[1];
      s16x8 r;
      r[0] = (short)f2bf(u.x); r[1] = (short)f2bf(u.y);
      r[2] = (short)f2bf(u.z); r[3] = (short)f2bf(u.w);
      r[4] = (short)f2bf(v.x); r[5] = (short)f2bf(v.y);
      r[6] = (short)f2bf(v.z); r[7] = (short)f2bf(v.w);
      ((s16x8*)xs)[((size_t)s * Nn + n) * 8 + off] = r;
    }
  }
}

// ---------------- scan (rowstart) + degree-bucketed node order ----------------

__global__ __launch_bounds__(1024) void scan_k(const int* __restrict__ deg,
                                               int* __restrict__ rowstart,
                                               unsigned short* __restrict__ nodeord, int n) {
  __shared__ int wsum[16];
  __shared__ int carry_s;
  __shared__ int hist[65];
  int tid = threadIdx.x;
  int lane = tid & 63, wid = tid >> 6;
  if (tid == 0) carry_s = 0;
  __syncthreads();
  for (int t0 = 0; t0 < n; t0 += 1024) {
    int i = t0 + tid;
    int v = (i < n) ? deg[i] : 0;
    int s = v;
#pragma unroll
    for (int off = 1; off < 64; off <<= 1) {
      int t = __shfl_up(s, off);
      if (lane >= off) s += t;
    }
    if (lane == 63) wsum[wid] = s;
    __syncthreads();
    if (wid == 0) {
      int ws = (lane < 16) ? wsum[lane] : 0;
#pragma unroll
      for (int off = 1; off < 16; off <<= 1) {
        int t = __shfl_up(ws, off);
        if (lane >= off) ws += t;
      }
      if (lane < 16) wsum[lane] = ws;
    }
    __syncthreads();
    int carry = carry_s;
    int wbase = (wid > 0) ? wsum[wid - 1] : 0;
    if (i < n) rowstart[i] = carry + wbase + s - v;
    int total = wsum[15];
    __syncthreads();
    if (tid == 0) carry_s = carry + total;
    __syncthreads();
  }
  if (tid == 0) rowstart[n] = carry_s;
  // ---- degree bucketing: nodeord = node ids sorted by min(deg,64) ----
  if (tid < 65) hist[tid] = 0;
  __syncthreads();
  for (int i = tid; i < n; i += 1024) atomicAdd(&hist[min(deg[i], 64)], 1);
  __syncthreads();
  if (tid == 0) {
    int run = 0;
    for (int b = 0; b < 65; ++b) { int c = hist[b]; hist[b] = run; run += c; }
  }
  __syncthreads();
  for (int i = tid; i < n; i += 1024) {
    int b = min(deg[i], 64);
    int pos = atomicAdd(&hist[b], 1);
    nodeord[pos] = (unsigned short)i;
  }
}

__global__ void fill_k(const int* __restrict__ src, const int* __restrict__ dst, int E,
                       const int* __restrict__ rowstart, int* __restrict__ cursor,
                       unsigned short* __restrict__ ep16) {
  int i = blockIdx.x * 256 + threadIdx.x;
  if (i < E) {
    int d = dst[i];
    int pos = atomicAdd(&cursor[d], 1);
    ep16[rowstart[d] + pos] = (unsigned short)src[i];
  }
}

// ---------------- slice-per-XCD aggregation ----------------

__global__ __launch_bounds__(256, 6) void agg_k(const unsigned short* __restrict__ xs,
                                                const int* __restrict__ rowstart,
                                                const unsigned short* __restrict__ ep16,
                                                const unsigned short* __restrict__ nodeord,
                                                unsigned short* __restrict__ h, int Nn) {
  int slice = blockIdx.x & 7;
  int nb = blockIdx.x >> 3;
  int wid = threadIdx.x >> 6, lane = threadIdx.x & 63;
  int g = lane >> 3, sub = lane & 7;
  int slot = (nb * 4 + wid) * 8 + g;
  int node = nodeord[slot];
  int beg = rowstart[node];
  int deg = rowstart[node + 1] - beg;
  int degm1 = max(deg - 1, 0);
  int dm = deg;
  dm = max(dm, __shfl_xor(dm, 8));
  dm = max(dm, __shfl_xor(dm, 16));
  dm = max(dm, __shfl_xor(dm, 32));
  const s16x8* sb = (const s16x8*)xs + (size_t)slice * Nn * 8;
  s16x8 own = sb[node * 8 + sub];
  float2 acc[4];
#pragma unroll
  for (int q = 0; q < 4; ++q) {
    unsigned int d = (unsigned int)((const int*)&own)[q];
    acc[q].x = bitsf(d << 16);
    acc[q].y = bitsf(d & 0xffff0000u);
  }
  for (int t = 0; t < dm; t += 4) {
    s16x8 v[4];
    float m[4];
#pragma unroll
    for (int b = 0; b < 4; ++b) {
      int tt = t + b;
      int e = ep16[beg + min(tt, degm1)];
      m[b] = (tt < deg) ? 1.f : 0.f;
      v[b] = sb[e * 8 + sub];
    }
#pragma unroll
    for (int b = 0; b < 4; ++b) {
#pragma unroll
      for (int q = 0; q < 4; ++q) {
        unsigned int d = (unsigned int)((const int*)&v[b])[q];
        acc[q].x = fmaf(m[b], bitsf(d << 16), acc[q].x);
        acc[q].y = fmaf(m[b], bitsf(d & 0xffff0000u), acc[q].y);
      }
    }
  }
  s16x8 r;
#pragma unroll
  for (int q = 0; q < 4; ++q) {
    r[q * 2 + 0] = (short)f2bf(acc[q].x);
    r[q * 2 + 1] = (short)f2bf(acc[q].y);
  }
  __builtin_nontemporal_store(r, (s16x8*)(h + (size_t)node * D_FEAT + slice * SLICE_D + sub * 8));
}

// ---------------- weights: Wt[n][k] = bf16(W[k][n]), LDS-tiled transpose ----------------

__global__ __launch_bounds__(256) void wconv_k(const float* __restrict__ W1,
                                               const float* __restrict__ W2,
                                               unsigned short* __restrict__ W1t,
                                               unsigned short* __restrict__ W2t) {
  __shared__ float tile[64][65];
  int t = blockIdx.x;
  const float* W = W1;
  unsigned short* Wt = W1t;
  if (t >= 64) { t -= 64; W = W2; Wt = W2t; }
  int tr = (t >> 3) * 64;
  int tc = (t & 7) * 64;
  int tid = threadIdx.x;
  int c4 = (tid & 15) * 4, rg = tid >> 4;
#pragma unroll
  for (int rr = 0; rr < 64; rr += 16) {
    int r = rr + rg;
    float4 vv = *(const float4*)&W[(size_t)(tr + r) * 512 + tc + c4];
    tile[r][c4] = vv.x; tile[r][c4 + 1] = vv.y; tile[r][c4 + 2] = vv.z; tile[r][c4 + 3] = vv.w;
  }
  __syncthreads();
  int ch = tid & 15;
#pragma unroll
  for (int rr = 0; rr < 64; rr += 16) {
    int n = rr + rg;
    int k0 = ch * 4;
    ushort4 o;
    o.x = f2bf(tile[k0 + 0][n]);
    o.y = f2bf(tile[k0 + 1][n]);
    o.z = f2bf(tile[k0 + 2][n]);
    o.w = f2bf(tile[k0 + 3][n]);
    *(ushort4*)&Wt[(size_t)(tc + n) * 512 + tr + k0] = o;
  }
}

// ---------------- GEMM v2: 128x128 tile, BK=32, TRIPLE-buffered LDS, depth-2 ----------------
// Counted vmcnt(4) in steady state (never 0 until last step): each tile's
// loads get a full compute phase + barriers to land; stalls overlap across
// ~2.5 resident blocks/CU. Two barriers/step make stage(t+2)->buf[(t-1)%3]
// WAR-safe (all waves passed compute(t-1) before barrier_B of step t).

template <int RELU, int OUTBF16>
__global__ __launch_bounds__(256) void gemm_k(const unsigned short* __restrict__ A,
                                              const unsigned short* __restrict__ Bt,
                                              const float* __restrict__ bias,
                                              void* __restrict__ Cout, int M) {
  const int K = 512;
  const int NSTEP = 16;  // K / 32
  __shared__ unsigned short As[3][128 * 32];
  __shared__ unsigned short Bs[3][128 * 32];
  int mt = (M + 127) >> 7;
  int qx = (mt + 7) >> 3;
  int b = blockIdx.x;
  int x = b & 7, i = b >> 3;
  int tm = x * qx + (i >> 2);
  int tn = i & 3;
  if (tm >= mt) return;
  int tid = threadIdx.x;
  int wave = tid >> 6, lane = tid & 63;
  int lr = lane & 15, lh = lane >> 4;
  int p3 = lr & 3;  // row&3 for all fragment rows this lane reads
  int wm = (wave >> 1) * 64, wn = (wave & 1) * 64;

  // stage one 128x32 A-tile + B-tile into buffer pb. 4 loads/wave (2 A, 2 B).
  auto stage = [&](int pb, int k0) {
#pragma unroll
    for (int ii = 0; ii < 2; ++ii) {
      int cb = ii * 256 + wave * 64 + lane;  // chunk id: row = cb>>2, slot = cb&3
      int row = cb >> 2;
      int cg = (cb & 3) ^ (row & 3);  // inverse-swizzled global chunk
      int ga = tm * 128 + row;
      if (ga > M - 1) ga = M - 1;
      async16(&As[pb][(size_t)(ii * 256 + wave * 64) * 8], A + (size_t)ga * K + k0 + cg * 8);
      int gb = tn * 128 + row;
      async16(&Bs[pb][(size_t)(ii * 256 + wave * 64) * 8], Bt + (size_t)gb * K + k0 + cg * 8);
    }
  };

  f32x4 zero = {0.f, 0.f, 0.f, 0.f};
  f32x4 acc[4][4];
#pragma unroll
  for (int m = 0; m < 4; ++m)
#pragma unroll
    for (int n = 0; n < 4; ++n) acc[m][n] = zero;

  stage(0, 0);
  stage(1, 32);

  for (int t = 0; t < NSTEP; ++t) {
    int pb = t % 3;
    if (t < NSTEP - 1)
      asm volatile("s_waitcnt vmcnt(4)" ::: "memory");  // tile t landed; t+1 in flight
    else
      asm volatile("s_waitcnt vmcnt(0)" ::: "memory");
    __builtin_amdgcn_s_barrier();
    s16x8 av[4], bv[4];
#pragma unroll
    for (int m = 0; m < 4; ++m) {
      int r = wm + m * 16 + lr;
      av[m] = *(const s16x8*)&As[pb][r * 32 + (lh ^ p3) * 8];
    }
#pragma unroll
    for (int n = 0; n < 4; ++n) {
      int r = wn + n * 16 + lr;
      bv[n] = *(const s16x8*)&Bs[pb][r * 32 + (lh ^ p3) * 8];
    }
#pragma unroll
    for (int m = 0; m < 4; ++m)
#pragma unroll
      for (int n = 0; n < 4; ++n)
        acc[m][n] = __builtin_amdgcn_mfma_f32_16x16x32_bf16(av[m], bv[n], acc[m][n], 0, 0, 0);
    __builtin_amdgcn_s_barrier();
    if (t + 2 < NSTEP) stage((t + 2) % 3, (t + 2) * 32);
  }

  // epilogue: C/D layout col=lane&15, row=(lane>>4)*4+j  [measured m89]
#pragma unroll
  for (int n = 0; n < 4; ++n) {
    int col = tn * 128 + wn + n * 16 + lr;
    float bval = bias[col];
#pragma unroll
    for (int m = 0; m < 4; ++m) {
#pragma unroll
      for (int j = 0; j < 4; ++j) {
        int row = tm * 128 + wm + m * 16 + lh * 4 + j;
        if (row < M) {
          float v = acc[m][n][j] + bval;
          if (RELU) v = fmaxf(v, 0.f);
          if (OUTBF16)
            ((unsigned short*)Cout)[(size_t)row * 512 + col] = f2bf(v);
          else
            ((float*)Cout)[(size_t)row * 512 + col] = v;
        }
      }
    }
  }
}

// ---------------- launch ----------------

extern "C" void kernel_launch(void* const* d_in, const int* in_sizes, int n_in,
                              void* d_out, int out_size, void* d_ws, size_t ws_size,
                              hipStream_t stream) {
  const float* x = (const float*)d_in[0];
  const int* ei = (const int*)d_in[1];
  const float* W1 = (const float*)d_in[2];
  const float* b1 = (const float*)d_in[3];
  const float* W2 = (const float*)d_in[4];
  const float* b2 = (const float*)d_in[5];
  const int N = in_sizes[0] / D_FEAT;  // 20000
  const int E = in_sizes[1] / 2;       // 640000
  const int* src = ei;
  const int* dst = ei + E;

  char* w = (char*)d_ws;
  auto alloc = [&](size_t bytes) {
    void* p = (void*)w;
    w += (bytes + 255) & ~(size_t)255;
    return p;
  };
  unsigned short* ep16 = (unsigned short*)alloc((size_t)E * 2 + 256);
  int* deg = (int*)alloc((size_t)N * 4);
  int* cursor = (int*)alloc((size_t)N * 4);  // adjacent to deg: one zero pass
  int* rowstart = (int*)alloc((size_t)(N + 1) * 4);
  unsigned short* nodeord = (unsigned short*)alloc((size_t)N * 2);
  unsigned short* W1t = (unsigned short*)alloc((size_t)512 * 512 * 2);
  unsigned short* W2t = (unsigned short*)alloc((size_t)512 * 512 * 2);
  unsigned short* c1 = (unsigned short*)alloc((size_t)N * 512 * 2);
  // h (bf16) = lower half of d_out; xs (slice-major bf16 x) = upper half.
  // Both dead before gemm2 overwrites d_out with the fp32 result.
  unsigned short* h = (unsigned short*)d_out;
  unsigned short* xs = (unsigned short*)d_out + (size_t)N * D_FEAT;

  size_t zbytes = (size_t)((char*)cursor - (char*)deg) + (size_t)N * 4;
  int zn16 = (int)(zbytes / 16);
  zero_k<<<(zn16 + 255) / 256, 256, 0, stream>>>((int4*)deg, zn16);
  int hb = (E + 255) / 256;                  // 2500
  int n8 = N * D_FEAT / 8;                   // 1.28M
  int xbk = (n8 + 255) / 256;                // 5000
  hx_k<<<hb + xbk, 256, 0, stream>>>(dst, E, deg, x, xs, n8, hb, N);
  scan_k<<<1, 1024, 0, stream>>>(deg, rowstart, nodeord, N);
  fill_k<<<hb, 256, 0, stream>>>(src, dst, E, rowstart, cursor, ep16);
  wconv_k<<<128, 256, 0, stream>>>(W1, W2, W1t, W2t);
  agg_k<<<8 * (N / 32), 256, 0, stream>>>(xs, rowstart, ep16, nodeord, h, N);
  int mt = (N + 127) / 128, qx = (mt + 7) / 8;
  int grid = 8 * qx * 4;
  gemm_k<1, 1><<<grid, 256, 0, stream>>>(h, W1t, b1, c1, N);
  gemm_k<0, 0><<<grid, 256, 0, stream>>>(c1, W2t, b2, d_out, N);
}